// Round 15
// baseline (322.287 us; speedup 1.0000x reference)
//
#include <hip/hip_runtime.h>
#include <hip/hip_bf16.h>
#include <cstdint>

// B=32, S=2048, H=1024.  M = B*S = 65536, N = K = 1024.
// out = [context (32*1024) | weights (32*2048)] f32.

typedef short s8v __attribute__((ext_vector_type(8)));   // 8 bf16 (4 VGPR)
typedef float f4v __attribute__((ext_vector_type(4)));   // MFMA acc

static __device__ __forceinline__ unsigned short f2bf(float f) {
  union { float f; uint32_t u; } x; x.f = f;
  uint32_t u = x.u;
  return (unsigned short)((u + 0x7FFFu + ((u >> 16) & 1u)) >> 16);  // RNE
}
static __device__ __forceinline__ float bf2f(unsigned short u) {
  union { float f; uint32_t u; } x; x.u = ((uint32_t)u) << 16; return x.f;
}
static __device__ __forceinline__ float fast_tanh(float x) {
  float e2 = __expf(2.0f * x);
  return 1.0f - 2.0f / (e2 + 1.0f);
}

#define GLL16(src, dst)                                                        \
  __builtin_amdgcn_global_load_lds(                                            \
      (const __attribute__((address_space(1))) void*)(src),                    \
      (__attribute__((address_space(3))) void*)(dst), 16, 0, 0)

#define WAITV(n) asm volatile("s_waitcnt vmcnt(" #n ")" ::: "memory")

// ---------------- f32 -> bf16 convert (keys only now) ----------------------
__global__ void cvt_kernel(const float* __restrict__ in, unsigned short* __restrict__ out, int n8) {
  int i = blockIdx.x * blockDim.x + threadIdx.x;
  int step = gridDim.x * blockDim.x;
  for (; i < n8; i += step) {
    const float4* p = (const float4*)(in + (size_t)i * 8);
    float4 a = p[0], b = p[1];
    union { unsigned short us[8]; uint4 v; } o;
    o.us[0] = f2bf(a.x); o.us[1] = f2bf(a.y); o.us[2] = f2bf(a.z); o.us[3] = f2bf(a.w);
    o.us[4] = f2bf(b.x); o.us[5] = f2bf(b.y); o.us[6] = f2bf(b.z); o.us[7] = f2bf(b.w);
    ((uint4*)out)[i] = o.v;
  }
}

// ---- q_proj + fused Ua cvt + fused zero-init of scores/ctx ----------------
// Grid 32x16 = 512 blocks x 256 threads = 131072 threads:
//   - each thread converts 8 Ua_w elems (1M total) to ua_bf
//   - threads 0..65535 zero scores; 65536..98303 zero ctx
//   - then the original qproj dot-products.
__global__ void qproj_kernel(const float* __restrict__ query, const float* __restrict__ Wa_w,
                             const float* __restrict__ Wa_b, const float* __restrict__ Ua_b,
                             const float* __restrict__ Ua_w, unsigned short* __restrict__ ua_bf,
                             float* __restrict__ scores, float* __restrict__ ctx,
                             float* __restrict__ qp) {
  int b = blockIdx.x, oc = blockIdx.y;          // 32 x 16 blocks
  int t = threadIdx.x;
  int lin = (oc * 32 + b) * 256 + t;            // 0..131071

  // fused zero-init
  if (lin < 65536) scores[lin] = 0.f;
  else if (lin < 98304) ctx[lin - 65536] = 0.f;

  // fused Ua cvt (8 elems/thread, exactly covers 1048576)
  {
    const float4* p = (const float4*)(Ua_w + (size_t)lin * 8);
    float4 a = p[0], c = p[1];
    union { unsigned short us[8]; uint4 v; } o;
    o.us[0] = f2bf(a.x); o.us[1] = f2bf(a.y); o.us[2] = f2bf(a.z); o.us[3] = f2bf(a.w);
    o.us[4] = f2bf(c.x); o.us[5] = f2bf(c.y); o.us[6] = f2bf(c.z); o.us[7] = f2bf(c.w);
    ((uint4*)ua_bf)[lin] = o.v;
  }

  __shared__ float qsh[1024];
  for (int i = t; i < 1024; i += 256) qsh[i] = query[b * 1024 + i];
  __syncthreads();
  int wid = t >> 6, lane = t & 63;
  const float4* q4 = (const float4*)qsh;
  for (int it = 0; it < 16; ++it) {
    int o = oc * 64 + it * 4 + wid;
    const float4* row = (const float4*)(Wa_w + (size_t)o * 1024);
    float s = 0.f;
#pragma unroll
    for (int j = 0; j < 4; ++j) {
      float4 w = row[j * 64 + lane];
      float4 q = q4[j * 64 + lane];
      s += w.x * q.x + w.y * q.y + w.z * q.z + w.w * q.w;
    }
#pragma unroll
    for (int m = 32; m; m >>= 1) s += __shfl_xor(s, m, 64);
    if (lane == 0) qp[b * 1024 + o] = s + Wa_b[o] + Ua_b[o];
  }
}

// ---------------- fused GEMM + tanh + Va-dot -> scores ---------------------
// Round-8 structure VERBATIM (best measured: 180 us, MfmaUtil 33.5%):
// 128x128 tile, BK=64, SINGLE-buffered 32 KB LDS, 2-phase
// {stage -> vmcnt0+barrier -> compute -> barrier}, 4 blocks/CU.
// Register knife-edge: 60 arch VGPR + 64 acc AGPR = 124 <= 128/wave @ 4w/SIMD.
// Conflict-free (r&7) chunk XOR swizzle both sides (measured 0 conflicts).
__global__ __launch_bounds__(256, 4) void gemm_score_sb(
    const unsigned short* __restrict__ keys_bf,
    const unsigned short* __restrict__ ua_bf,
    const float* __restrict__ qp, const float* __restrict__ va,
    float* __restrict__ scores) {
  __shared__ unsigned short ldsA[128 * 64];   // 16 KB
  __shared__ unsigned short ldsB[128 * 64];   // 16 KB

  int bid = blockIdx.x;                       // 4096 blocks
  int wg  = (bid & 7) * 512 + (bid >> 3);     // bijective XCD swizzle
  int mt  = wg >> 3;                          // 0..511
  int nt  = wg & 7;                           // 0..7
  int t   = threadIdx.x;
  int wid = t >> 6, lane = t & 63;
  int wm = wid >> 1, wn = wid & 1;            // 2x2 waves, each 64x64
  int lr = lane & 15, lk = lane >> 4;

  f4v acc[4][4];
#pragma unroll
  for (int mi = 0; mi < 4; ++mi)
#pragma unroll
    for (int ni = 0; ni < 4; ++ni) acc[mi][ni] = (f4v){0.f, 0.f, 0.f, 0.f};

  // staging: linear slot u = i*256+t; row r = u>>3 (0..127), slot s = u&7
  // holds global 16B-chunk c = s ^ (r&7)  (both-sides XOR swizzle).
  const unsigned short* srcA[4];
  const unsigned short* srcB[4];
  int dstOff[4];
#pragma unroll
  for (int i = 0; i < 4; ++i) {
    int u = i * 256 + t;
    int r = u >> 3;
    int c = (u & 7) ^ (r & 7);
    srcA[i] = keys_bf + (size_t)(mt * 128 + r) * 1024 + c * 8;
    srcB[i] = ua_bf  + (size_t)(nt * 128 + r) * 1024 + c * 8;
    dstOff[i] = u * 8;               // ushort units
  }

  // read offsets: frag (kk,mi): row = base+mi*16+lr, chunk kk*4+lk at slot
  // (kk*4+lk)^(lr&7).  Measured conflict-free (rounds 5/6/8).
  int offA[2][4], offB[2][4];
#pragma unroll
  for (int kk = 0; kk < 2; ++kk) {
#pragma unroll
    for (int mi = 0; mi < 4; ++mi)
      offA[kk][mi] = (wm * 64 + mi * 16 + lr) * 64 + (((kk * 4 + lk) ^ (lr & 7)) * 8);
#pragma unroll
    for (int ni = 0; ni < 4; ++ni)
      offB[kk][ni] = (wn * 64 + ni * 16 + lr) * 64 + (((kk * 4 + lk) ^ (lr & 7)) * 8);
  }

  for (int kt = 0; kt < 16; ++kt) {
    // ---- stage phase: 8 GLL16 per thread (A 4 + B 4)
#pragma unroll
    for (int i = 0; i < 4; ++i) {
      GLL16(srcA[i] + kt * 64, ldsA + dstOff[i]);
      GLL16(srcB[i] + kt * 64, ldsB + dstOff[i]);
    }
    WAITV(0);
    __syncthreads();
    // ---- compute phase: 16 ds_read_b128 + 32 MFMA
#pragma unroll
    for (int kk = 0; kk < 2; ++kk) {
      s8v a[4], b[4];
#pragma unroll
      for (int mi = 0; mi < 4; ++mi) a[mi] = *(const s8v*)(ldsA + offA[kk][mi]);
#pragma unroll
      for (int ni = 0; ni < 4; ++ni) b[ni] = *(const s8v*)(ldsB + offB[kk][ni]);
#pragma unroll
      for (int mi = 0; mi < 4; ++mi)
#pragma unroll
        for (int ni = 0; ni < 4; ++ni)
          acc[mi][ni] = __builtin_amdgcn_mfma_f32_16x16x32_bf16(a[mi], b[ni], acc[mi][ni], 0, 0, 0);
    }
    __syncthreads();
  }

  // epilogue: tanh + Va-weighted reduce over the 128 columns of this N-tile
  int b = mt >> 4;
  float qv[4], vv[4];
#pragma unroll
  for (int ni = 0; ni < 4; ++ni) {
    int o = nt * 128 + wn * 64 + ni * 16 + lr;
    qv[ni] = qp[b * 1024 + o];
    vv[ni] = va[o];
  }
#pragma unroll
  for (int mi = 0; mi < 4; ++mi) {
#pragma unroll
    for (int r = 0; r < 4; ++r) {
      float sum = 0.f;
#pragma unroll
      for (int ni = 0; ni < 4; ++ni)
        sum += vv[ni] * fast_tanh(acc[mi][ni][r] + qv[ni]);
      sum += __shfl_xor(sum, 1, 64);
      sum += __shfl_xor(sum, 2, 64);
      sum += __shfl_xor(sum, 4, 64);
      sum += __shfl_xor(sum, 8, 64);
      if (lr == 0)
        atomicAdd(&scores[(size_t)mt * 128 + wm * 64 + mi * 16 + lk * 4 + r], sum);
    }
  }
}

// ---------------- fallback (f32 keys direct, small ws) ---------------------
__global__ __launch_bounds__(256, 2) void gemm_score_fallback(
    const float* __restrict__ keys_f, const unsigned short* __restrict__ ua_bf,
    const float* __restrict__ qp, const float* __restrict__ va,
    float* __restrict__ scores) {
  __shared__ unsigned short ldsA[2][128 * 64];
  __shared__ unsigned short ldsB[2][128 * 64];
  int bid = blockIdx.x;
  int wg  = (bid & 7) * 512 + (bid >> 3);
  int mt  = wg >> 3, nt = wg & 7;
  int t   = threadIdx.x;
  int wid = t >> 6, lane = t & 63;
  int wm = wid >> 1, wn = wid & 1;
  int lr = lane & 15, lk = lane >> 4;
  f4v acc[4][4];
#pragma unroll
  for (int mi = 0; mi < 4; ++mi)
#pragma unroll
    for (int ni = 0; ni < 4; ++ni) acc[mi][ni] = (f4v){0.f, 0.f, 0.f, 0.f};
  int colb = (t & 7) * 8;
  auto stage = [&](int kt, int buf) {
#pragma unroll
    for (int i = 0; i < 4; ++i) {
      int flat = i * 256 + t;
      int row  = flat >> 3;
      const float4* src = (const float4*)(keys_f + (size_t)(mt * 128 + row) * 1024 + kt * 64 + colb);
      float4 a = src[0], c = src[1];
      union { unsigned short us[8]; s8v v; } o;
      o.us[0] = f2bf(a.x); o.us[1] = f2bf(a.y); o.us[2] = f2bf(a.z); o.us[3] = f2bf(a.w);
      o.us[4] = f2bf(c.x); o.us[5] = f2bf(c.y); o.us[6] = f2bf(c.z); o.us[7] = f2bf(c.w);
      *(s8v*)&ldsA[buf][flat * 8] = o.v;
      const unsigned short* srcB = ua_bf + (size_t)(nt * 128 + row) * 1024 + kt * 64 + colb;
      GLL16(srcB, &ldsB[buf][flat * 8]);
    }
  };
  auto compute = [&](int buf) {
#pragma unroll
    for (int kk = 0; kk < 2; ++kk) {
      s8v af[4], bfr[4];
#pragma unroll
      for (int mi = 0; mi < 4; ++mi)
        af[mi] = *(const s8v*)&ldsA[buf][(wm * 64 + mi * 16 + lr) * 64 + kk * 32 + lk * 8];
#pragma unroll
      for (int ni = 0; ni < 4; ++ni)
        bfr[ni] = *(const s8v*)&ldsB[buf][(wn * 64 + ni * 16 + lr) * 64 + kk * 32 + lk * 8];
#pragma unroll
      for (int mi = 0; mi < 4; ++mi)
#pragma unroll
        for (int ni = 0; ni < 4; ++ni)
          acc[mi][ni] = __builtin_amdgcn_mfma_f32_16x16x32_bf16(af[mi], bfr[ni], acc[mi][ni], 0, 0, 0);
    }
  };
  stage(0, 0);
  for (int kt = 0; kt < 16; ++kt) {
    __syncthreads();
    if (kt + 1 < 16) stage(kt + 1, (kt + 1) & 1);
    compute(kt & 1);
  }
  int b = mt >> 4;
  float qv[4], vv[4];
#pragma unroll
  for (int ni = 0; ni < 4; ++ni) {
    int o = nt * 128 + wn * 64 + ni * 16 + lr;
    qv[ni] = qp[b * 1024 + o];
    vv[ni] = va[o];
  }
#pragma unroll
  for (int mi = 0; mi < 4; ++mi) {
#pragma unroll
    for (int r = 0; r < 4; ++r) {
      float sum = 0.f;
#pragma unroll
      for (int ni = 0; ni < 4; ++ni)
        sum += vv[ni] * fast_tanh(acc[mi][ni][r] + qv[ni]);
      sum += __shfl_xor(sum, 1, 64);
      sum += __shfl_xor(sum, 2, 64);
      sum += __shfl_xor(sum, 4, 64);
      sum += __shfl_xor(sum, 8, 64);
      if (lr == 0)
        atomicAdd(&scores[(size_t)mt * 128 + wm * 64 + mi * 16 + lk * 4 + r], sum);
    }
  }
}

// ---------------- softmax over S=2048 per batch ----------------------------
__global__ void softmax_kernel(const float* __restrict__ scores, float* __restrict__ w) {
  int b = blockIdx.x, t = threadIdx.x;
  int wid = t >> 6, lane = t & 63;
  __shared__ float redm[4], reds[4];
  const float4* src = (const float4*)(scores + b * 2048 + t * 8);
  float4 x = src[0], y = src[1];
  float v[8] = {x.x, x.y, x.z, x.w, y.x, y.y, y.z, y.w};
  float mx = v[0];
#pragma unroll
  for (int j = 1; j < 8; ++j) mx = fmaxf(mx, v[j]);
#pragma unroll
  for (int m = 32; m; m >>= 1) mx = fmaxf(mx, __shfl_xor(mx, m, 64));
  if (lane == 0) redm[wid] = mx;
  __syncthreads();
  mx = fmaxf(fmaxf(redm[0], redm[1]), fmaxf(redm[2], redm[3]));
  float e[8], s = 0.f;
#pragma unroll
  for (int j = 0; j < 8; ++j) { e[j] = __expf(v[j] - mx); s += e[j]; }
#pragma unroll
  for (int m = 32; m; m >>= 1) s += __shfl_xor(s, m, 64);
  if (lane == 0) reds[wid] = s;
  __syncthreads();
  float inv = 1.f / (reds[0] + reds[1] + reds[2] + reds[3]);
  float4 o0 = {e[0] * inv, e[1] * inv, e[2] * inv, e[3] * inv};
  float4 o1 = {e[4] * inv, e[5] * inv, e[6] * inv, e[7] * inv};
  float4* dst = (float4*)(w + b * 2048 + t * 8);
  dst[0] = o0; dst[1] = o1;
}

// ---------------- context[b,h] = sum_s w[b,s]*keys[b,s,h] ------------------
// 16B/lane (8 bf16) loads; 256 threads cover 2 rows per iter; w wave-uniform.
template<bool KBF>
__global__ void context_kernel(const unsigned short* __restrict__ keys_bf,
                               const float* __restrict__ keys_f,
                               const float* __restrict__ w, float* __restrict__ ctx) {
  int b = blockIdx.y, sc = blockIdx.x, t = threadIdx.x;   // 32 sc x 32 b
  int rowoff = t >> 7;               // 0..1 (wave-uniform)
  int h = (t & 127) * 8;
  float a[8] = {0, 0, 0, 0, 0, 0, 0, 0};
  for (int s0 = 0; s0 < 64; s0 += 2) {
    int s = sc * 64 + s0 + rowoff;
    float ws = w[b * 2048 + s];
    if constexpr (KBF) {
      uint4 kv = *(const uint4*)(keys_bf + ((size_t)(b * 2048 + s)) * 1024 + h);
      const unsigned short* u = (const unsigned short*)&kv;
#pragma unroll
      for (int j = 0; j < 8; ++j) a[j] += ws * bf2f(u[j]);
    } else {
      const float4* kp = (const float4*)(keys_f + ((size_t)(b * 2048 + s)) * 1024 + h);
      float4 k0 = kp[0], k1 = kp[1];
      a[0] += ws * k0.x; a[1] += ws * k0.y; a[2] += ws * k0.z; a[3] += ws * k0.w;
      a[4] += ws * k1.x; a[5] += ws * k1.y; a[6] += ws * k1.z; a[7] += ws * k1.w;
    }
  }
#pragma unroll
  for (int j = 0; j < 8; ++j) atomicAdd(&ctx[b * 1024 + h + j], a[j]);
}

extern "C" void kernel_launch(void* const* d_in, const int* in_sizes, int n_in,
                              void* d_out, int out_size, void* d_ws, size_t ws_size,
                              hipStream_t stream) {
  const float* query = (const float*)d_in[0];
  const float* keys  = (const float*)d_in[1];
  const float* Wa_w  = (const float*)d_in[2];
  const float* Wa_b  = (const float*)d_in[3];
  const float* Ua_w  = (const float*)d_in[4];
  const float* Ua_b  = (const float*)d_in[5];
  const float* Va_w  = (const float*)d_in[6];
  // Va_b cancels in softmax.

  float* out = (float*)d_out;
  float* ctx = out;            // [32,1024]
  float* wts = out + 32768;    // [32,2048]

  char* ws = (char*)d_ws;
  unsigned short* ua_bf   = (unsigned short*)ws;                       // 2 MB
  float*          qp      = (float*)(ws + 2 * 1024 * 1024);            // 128 KB
  float*          scores  = (float*)(ws + 2 * 1024 * 1024 + 131072);   // 256 KB
  unsigned short* keys_bf = (unsigned short*)(ws + 2 * 1024 * 1024 + 131072 + 262144);
  const size_t need_big = 2ull * 1024 * 1024 + 131072 + 262144 + 67108864ull * 2;
  bool big = ws_size >= need_big;

  // qproj fuses: Ua cvt, scores/ctx zero-init, q-projection.
  qproj_kernel<<<dim3(32, 16), 256, 0, stream>>>(query, Wa_w, Wa_b, Ua_b,
                                                 Ua_w, ua_bf, scores, ctx, qp);

  if (big) cvt_kernel<<<2048, 256, 0, stream>>>(keys, keys_bf, 67108864 / 8);

  if (big) gemm_score_sb<<<4096, 256, 0, stream>>>(keys_bf, ua_bf, qp, Va_w, scores);
  else     gemm_score_fallback<<<4096, 256, 0, stream>>>(keys, ua_bf, qp, Va_w, scores);

  softmax_kernel<<<32, 256, 0, stream>>>(scores, wts);

  if (big) context_kernel<true ><<<dim3(32, 32), 256, 0, stream>>>(keys_bf, nullptr, wts, ctx);
  else     context_kernel<false><<<dim3(32, 32), 256, 0, stream>>>(nullptr, keys, wts, ctx);
}

// Round 16
// 280.691 us; speedup vs baseline: 1.1482x; 1.1482x over previous
//
#include <hip/hip_runtime.h>
#include <hip/hip_bf16.h>
#include <cstdint>

// B=32, S=2048, H=1024.  M = B*S = 65536, N = K = 1024.
// out = [context (32*1024) | weights (32*2048)] f32.

typedef short s8v __attribute__((ext_vector_type(8)));   // 8 bf16 (4 VGPR)
typedef float f4v __attribute__((ext_vector_type(4)));   // MFMA acc

static __device__ __forceinline__ unsigned short f2bf(float f) {
  union { float f; uint32_t u; } x; x.f = f;
  uint32_t u = x.u;
  return (unsigned short)((u + 0x7FFFu + ((u >> 16) & 1u)) >> 16);  // RNE
}
static __device__ __forceinline__ float bf2f(unsigned short u) {
  union { float f; uint32_t u; } x; x.u = ((uint32_t)u) << 16; return x.f;
}
static __device__ __forceinline__ float fast_tanh(float x) {
  float e2 = __expf(2.0f * x);
  return 1.0f - 2.0f / (e2 + 1.0f);
}

#define GLL16(src, dst)                                                        \
  __builtin_amdgcn_global_load_lds(                                            \
      (const __attribute__((address_space(1))) void*)(src),                    \
      (__attribute__((address_space(3))) void*)(dst), 16, 0, 0)

#define WAITV(n) asm volatile("s_waitcnt vmcnt(" #n ")" ::: "memory")

// ---------------- f32 -> bf16 convert (keys only) --------------------------
__global__ void cvt_kernel(const float* __restrict__ in, unsigned short* __restrict__ out, int n8) {
  int i = blockIdx.x * blockDim.x + threadIdx.x;
  int step = gridDim.x * blockDim.x;
  for (; i < n8; i += step) {
    const float4* p = (const float4*)(in + (size_t)i * 8);
    float4 a = p[0], b = p[1];
    union { unsigned short us[8]; uint4 v; } o;
    o.us[0] = f2bf(a.x); o.us[1] = f2bf(a.y); o.us[2] = f2bf(a.z); o.us[3] = f2bf(a.w);
    o.us[4] = f2bf(b.x); o.us[5] = f2bf(b.y); o.us[6] = f2bf(b.z); o.us[7] = f2bf(b.w);
    ((uint4*)out)[i] = o.v;
  }
}

// ---- q_proj + fused Ua cvt + fused zero-init of scores/ctx ----------------
__global__ void qproj_kernel(const float* __restrict__ query, const float* __restrict__ Wa_w,
                             const float* __restrict__ Wa_b, const float* __restrict__ Ua_b,
                             const float* __restrict__ Ua_w, unsigned short* __restrict__ ua_bf,
                             float* __restrict__ scores, float* __restrict__ ctx,
                             float* __restrict__ qp) {
  int b = blockIdx.x, oc = blockIdx.y;          // 32 x 16 blocks
  int t = threadIdx.x;
  int lin = (oc * 32 + b) * 256 + t;            // 0..131071

  // fused zero-init
  if (lin < 65536) scores[lin] = 0.f;
  else if (lin < 98304) ctx[lin - 65536] = 0.f;

  // fused Ua cvt (8 elems/thread, exactly covers 1048576)
  {
    const float4* p = (const float4*)(Ua_w + (size_t)lin * 8);
    float4 a = p[0], c = p[1];
    union { unsigned short us[8]; uint4 v; } o;
    o.us[0] = f2bf(a.x); o.us[1] = f2bf(a.y); o.us[2] = f2bf(a.z); o.us[3] = f2bf(a.w);
    o.us[4] = f2bf(c.x); o.us[5] = f2bf(c.y); o.us[6] = f2bf(c.z); o.us[7] = f2bf(c.w);
    ((uint4*)ua_bf)[lin] = o.v;
  }

  __shared__ float qsh[1024];
  for (int i = t; i < 1024; i += 256) qsh[i] = query[b * 1024 + i];
  __syncthreads();
  int wid = t >> 6, lane = t & 63;
  const float4* q4 = (const float4*)qsh;
  for (int it = 0; it < 16; ++it) {
    int o = oc * 64 + it * 4 + wid;
    const float4* row = (const float4*)(Wa_w + (size_t)o * 1024);
    float s = 0.f;
#pragma unroll
    for (int j = 0; j < 4; ++j) {
      float4 w = row[j * 64 + lane];
      float4 q = q4[j * 64 + lane];
      s += w.x * q.x + w.y * q.y + w.z * q.z + w.w * q.w;
    }
#pragma unroll
    for (int m = 32; m; m >>= 1) s += __shfl_xor(s, m, 64);
    if (lane == 0) qp[b * 1024 + o] = s + Wa_b[o] + Ua_b[o];
  }
}

// ---------------- fused GEMM + tanh + Va-dot -> scores ---------------------
// Round-8 structure VERBATIM (best measured: 180 us, MfmaUtil 33.5%):
// 128x128 tile, BK=64, SINGLE-buffered 32 KB LDS, 2-phase
// {stage -> vmcnt0+barrier -> compute -> barrier}, 4 blocks/CU.
// Register knife-edge: 60 arch VGPR + 64 acc AGPR = 124 <= 128/wave @ 4w/SIMD.
// Conflict-free (r&7) chunk XOR swizzle both sides (measured 0 conflicts).
__global__ __launch_bounds__(256, 4) void gemm_score_sb(
    const unsigned short* __restrict__ keys_bf,
    const unsigned short* __restrict__ ua_bf,
    const float* __restrict__ qp, const float* __restrict__ va,
    float* __restrict__ scores) {
  __shared__ unsigned short ldsA[128 * 64];   // 16 KB
  __shared__ unsigned short ldsB[128 * 64];   // 16 KB

  int bid = blockIdx.x;                       // 4096 blocks
  int wg  = (bid & 7) * 512 + (bid >> 3);     // bijective XCD swizzle
  int mt  = wg >> 3;                          // 0..511
  int nt  = wg & 7;                           // 0..7
  int t   = threadIdx.x;
  int wid = t >> 6, lane = t & 63;
  int wm = wid >> 1, wn = wid & 1;            // 2x2 waves, each 64x64
  int lr = lane & 15, lk = lane >> 4;

  f4v acc[4][4];
#pragma unroll
  for (int mi = 0; mi < 4; ++mi)
#pragma unroll
    for (int ni = 0; ni < 4; ++ni) acc[mi][ni] = (f4v){0.f, 0.f, 0.f, 0.f};

  const unsigned short* srcA[4];
  const unsigned short* srcB[4];
  int dstOff[4];
#pragma unroll
  for (int i = 0; i < 4; ++i) {
    int u = i * 256 + t;
    int r = u >> 3;
    int c = (u & 7) ^ (r & 7);
    srcA[i] = keys_bf + (size_t)(mt * 128 + r) * 1024 + c * 8;
    srcB[i] = ua_bf  + (size_t)(nt * 128 + r) * 1024 + c * 8;
    dstOff[i] = u * 8;               // ushort units
  }

  int offA[2][4], offB[2][4];
#pragma unroll
  for (int kk = 0; kk < 2; ++kk) {
#pragma unroll
    for (int mi = 0; mi < 4; ++mi)
      offA[kk][mi] = (wm * 64 + mi * 16 + lr) * 64 + (((kk * 4 + lk) ^ (lr & 7)) * 8);
#pragma unroll
    for (int ni = 0; ni < 4; ++ni)
      offB[kk][ni] = (wn * 64 + ni * 16 + lr) * 64 + (((kk * 4 + lk) ^ (lr & 7)) * 8);
  }

  for (int kt = 0; kt < 16; ++kt) {
#pragma unroll
    for (int i = 0; i < 4; ++i) {
      GLL16(srcA[i] + kt * 64, ldsA + dstOff[i]);
      GLL16(srcB[i] + kt * 64, ldsB + dstOff[i]);
    }
    WAITV(0);
    __syncthreads();
#pragma unroll
    for (int kk = 0; kk < 2; ++kk) {
      s8v a[4], b[4];
#pragma unroll
      for (int mi = 0; mi < 4; ++mi) a[mi] = *(const s8v*)(ldsA + offA[kk][mi]);
#pragma unroll
      for (int ni = 0; ni < 4; ++ni) b[ni] = *(const s8v*)(ldsB + offB[kk][ni]);
#pragma unroll
      for (int mi = 0; mi < 4; ++mi)
#pragma unroll
        for (int ni = 0; ni < 4; ++ni)
          acc[mi][ni] = __builtin_amdgcn_mfma_f32_16x16x32_bf16(a[mi], b[ni], acc[mi][ni], 0, 0, 0);
    }
    __syncthreads();
  }

  int b = mt >> 4;
  float qv[4], vv[4];
#pragma unroll
  for (int ni = 0; ni < 4; ++ni) {
    int o = nt * 128 + wn * 64 + ni * 16 + lr;
    qv[ni] = qp[b * 1024 + o];
    vv[ni] = va[o];
  }
#pragma unroll
  for (int mi = 0; mi < 4; ++mi) {
#pragma unroll
    for (int r = 0; r < 4; ++r) {
      float sum = 0.f;
#pragma unroll
      for (int ni = 0; ni < 4; ++ni)
        sum += vv[ni] * fast_tanh(acc[mi][ni][r] + qv[ni]);
      sum += __shfl_xor(sum, 1, 64);
      sum += __shfl_xor(sum, 2, 64);
      sum += __shfl_xor(sum, 4, 64);
      sum += __shfl_xor(sum, 8, 64);
      if (lr == 0)
        atomicAdd(&scores[(size_t)mt * 128 + wm * 64 + mi * 16 + lk * 4 + r], sum);
    }
  }
}

// ---------------- fallback (f32 keys direct, small ws) ---------------------
__global__ __launch_bounds__(256, 2) void gemm_score_fallback(
    const float* __restrict__ keys_f, const unsigned short* __restrict__ ua_bf,
    const float* __restrict__ qp, const float* __restrict__ va,
    float* __restrict__ scores) {
  __shared__ unsigned short ldsA[2][128 * 64];
  __shared__ unsigned short ldsB[2][128 * 64];
  int bid = blockIdx.x;
  int wg  = (bid & 7) * 512 + (bid >> 3);
  int mt  = wg >> 3, nt = wg & 7;
  int t   = threadIdx.x;
  int wid = t >> 6, lane = t & 63;
  int wm = wid >> 1, wn = wid & 1;
  int lr = lane & 15, lk = lane >> 4;
  f4v acc[4][4];
#pragma unroll
  for (int mi = 0; mi < 4; ++mi)
#pragma unroll
    for (int ni = 0; ni < 4; ++ni) acc[mi][ni] = (f4v){0.f, 0.f, 0.f, 0.f};
  int colb = (t & 7) * 8;
  auto stage = [&](int kt, int buf) {
#pragma unroll
    for (int i = 0; i < 4; ++i) {
      int flat = i * 256 + t;
      int row  = flat >> 3;
      const float4* src = (const float4*)(keys_f + (size_t)(mt * 128 + row) * 1024 + kt * 64 + colb);
      float4 a = src[0], c = src[1];
      union { unsigned short us[8]; s8v v; } o;
      o.us[0] = f2bf(a.x); o.us[1] = f2bf(a.y); o.us[2] = f2bf(a.z); o.us[3] = f2bf(a.w);
      o.us[4] = f2bf(c.x); o.us[5] = f2bf(c.y); o.us[6] = f2bf(c.z); o.us[7] = f2bf(c.w);
      *(s8v*)&ldsA[buf][flat * 8] = o.v;
      const unsigned short* srcB = ua_bf + (size_t)(nt * 128 + row) * 1024 + kt * 64 + colb;
      GLL16(srcB, &ldsB[buf][flat * 8]);
    }
  };
  auto compute = [&](int buf) {
#pragma unroll
    for (int kk = 0; kk < 2; ++kk) {
      s8v af[4], bfr[4];
#pragma unroll
      for (int mi = 0; mi < 4; ++mi)
        af[mi] = *(const s8v*)&ldsA[buf][(wm * 64 + mi * 16 + lr) * 64 + kk * 32 + lk * 8];
#pragma unroll
      for (int ni = 0; ni < 4; ++ni)
        bfr[ni] = *(const s8v*)&ldsB[buf][(wn * 64 + ni * 16 + lr) * 64 + kk * 32 + lk * 8];
#pragma unroll
      for (int mi = 0; mi < 4; ++mi)
#pragma unroll
        for (int ni = 0; ni < 4; ++ni)
          acc[mi][ni] = __builtin_amdgcn_mfma_f32_16x16x32_bf16(af[mi], bfr[ni], acc[mi][ni], 0, 0, 0);
    }
  };
  stage(0, 0);
  for (int kt = 0; kt < 16; ++kt) {
    __syncthreads();
    if (kt + 1 < 16) stage(kt + 1, (kt + 1) & 1);
    compute(kt & 1);
  }
  int b = mt >> 4;
  float qv[4], vv[4];
#pragma unroll
  for (int ni = 0; ni < 4; ++ni) {
    int o = nt * 128 + wn * 64 + ni * 16 + lr;
    qv[ni] = qp[b * 1024 + o];
    vv[ni] = va[o];
  }
#pragma unroll
  for (int mi = 0; mi < 4; ++mi) {
#pragma unroll
    for (int r = 0; r < 4; ++r) {
      float sum = 0.f;
#pragma unroll
      for (int ni = 0; ni < 4; ++ni)
        sum += vv[ni] * fast_tanh(acc[mi][ni][r] + qv[ni]);
      sum += __shfl_xor(sum, 1, 64);
      sum += __shfl_xor(sum, 2, 64);
      sum += __shfl_xor(sum, 4, 64);
      sum += __shfl_xor(sum, 8, 64);
      if (lr == 0)
        atomicAdd(&scores[(size_t)mt * 128 + wm * 64 + mi * 16 + lk * 4 + r], sum);
    }
  }
}

// ---------------- softmax over S=2048 per batch ----------------------------
__global__ void softmax_kernel(const float* __restrict__ scores, float* __restrict__ w) {
  int b = blockIdx.x, t = threadIdx.x;
  int wid = t >> 6, lane = t & 63;
  __shared__ float redm[4], reds[4];
  const float4* src = (const float4*)(scores + b * 2048 + t * 8);
  float4 x = src[0], y = src[1];
  float v[8] = {x.x, x.y, x.z, x.w, y.x, y.y, y.z, y.w};
  float mx = v[0];
#pragma unroll
  for (int j = 1; j < 8; ++j) mx = fmaxf(mx, v[j]);
#pragma unroll
  for (int m = 32; m; m >>= 1) mx = fmaxf(mx, __shfl_xor(mx, m, 64));
  if (lane == 0) redm[wid] = mx;
  __syncthreads();
  mx = fmaxf(fmaxf(redm[0], redm[1]), fmaxf(redm[2], redm[3]));
  float e[8], s = 0.f;
#pragma unroll
  for (int j = 0; j < 8; ++j) { e[j] = __expf(v[j] - mx); s += e[j]; }
#pragma unroll
  for (int m = 32; m; m >>= 1) s += __shfl_xor(s, m, 64);
  if (lane == 0) reds[wid] = s;
  __syncthreads();
  float inv = 1.f / (reds[0] + reds[1] + reds[2] + reds[3]);
  float4 o0 = {e[0] * inv, e[1] * inv, e[2] * inv, e[3] * inv};
  float4 o1 = {e[4] * inv, e[5] * inv, e[6] * inv, e[7] * inv};
  float4* dst = (float4*)(w + b * 2048 + t * 8);
  dst[0] = o0; dst[1] = o1;
}

// ---------------- context[b,h] = sum_s w[b,s]*keys[b,s,h] ------------------
// Round-8 version (measured within the 292 us total): 4 cols/thread,
// 64 s-rows per block, 1M atomics total.
template<bool KBF>
__global__ void context_kernel(const unsigned short* __restrict__ keys_bf,
                               const float* __restrict__ keys_f,
                               const float* __restrict__ w, float* __restrict__ ctx) {
  int b = blockIdx.y, sc = blockIdx.x, t = threadIdx.x;   // 32 s-chunks x 32 b
  int h = t * 4;
  float a0 = 0, a1 = 0, a2 = 0, a3 = 0;
  for (int s0 = 0; s0 < 64; ++s0) {
    int s = sc * 64 + s0;
    float ws = w[b * 2048 + s];
    if constexpr (KBF) {
      ushort4 kv = *(const ushort4*)(keys_bf + ((size_t)(b * 2048 + s)) * 1024 + h);
      a0 += ws * bf2f(kv.x); a1 += ws * bf2f(kv.y);
      a2 += ws * bf2f(kv.z); a3 += ws * bf2f(kv.w);
    } else {
      float4 kv = *(const float4*)(keys_f + ((size_t)(b * 2048 + s)) * 1024 + h);
      a0 += ws * kv.x; a1 += ws * kv.y; a2 += ws * kv.z; a3 += ws * kv.w;
    }
  }
  atomicAdd(&ctx[b * 1024 + h + 0], a0);
  atomicAdd(&ctx[b * 1024 + h + 1], a1);
  atomicAdd(&ctx[b * 1024 + h + 2], a2);
  atomicAdd(&ctx[b * 1024 + h + 3], a3);
}

extern "C" void kernel_launch(void* const* d_in, const int* in_sizes, int n_in,
                              void* d_out, int out_size, void* d_ws, size_t ws_size,
                              hipStream_t stream) {
  const float* query = (const float*)d_in[0];
  const float* keys  = (const float*)d_in[1];
  const float* Wa_w  = (const float*)d_in[2];
  const float* Wa_b  = (const float*)d_in[3];
  const float* Ua_w  = (const float*)d_in[4];
  const float* Ua_b  = (const float*)d_in[5];
  const float* Va_w  = (const float*)d_in[6];
  // Va_b cancels in softmax.

  float* out = (float*)d_out;
  float* ctx = out;            // [32,1024]
  float* wts = out + 32768;    // [32,2048]

  char* ws = (char*)d_ws;
  unsigned short* ua_bf   = (unsigned short*)ws;                       // 2 MB
  float*          qp      = (float*)(ws + 2 * 1024 * 1024);            // 128 KB
  float*          scores  = (float*)(ws + 2 * 1024 * 1024 + 131072);   // 256 KB
  unsigned short* keys_bf = (unsigned short*)(ws + 2 * 1024 * 1024 + 131072 + 262144);
  const size_t need_big = 2ull * 1024 * 1024 + 131072 + 262144 + 67108864ull * 2;
  bool big = ws_size >= need_big;

  // qproj fuses: Ua cvt, scores/ctx zero-init, q-projection.
  qproj_kernel<<<dim3(32, 16), 256, 0, stream>>>(query, Wa_w, Wa_b, Ua_b,
                                                 Ua_w, ua_bf, scores, ctx, qp);

  if (big) cvt_kernel<<<2048, 256, 0, stream>>>(keys, keys_bf, 67108864 / 8);

  if (big) gemm_score_sb<<<4096, 256, 0, stream>>>(keys_bf, ua_bf, qp, Va_w, scores);
  else     gemm_score_fallback<<<4096, 256, 0, stream>>>(keys, ua_bf, qp, Va_w, scores);

  softmax_kernel<<<32, 256, 0, stream>>>(scores, wts);

  if (big) context_kernel<true ><<<dim3(32, 32), 256, 0, stream>>>(keys_bf, nullptr, wts, ctx);
  else     context_kernel<false><<<dim3(32, 32), 256, 0, stream>>>(nullptr, keys, wts, ctx);
}